// Round 8
// baseline (1392.373 us; speedup 1.0000x reference)
//
#include <hip/hip_runtime.h>
#include <cstdint>

#define NN 65536
#define EE 524288
#define BS_ 16

typedef unsigned short u16;
typedef unsigned int u32;
typedef __attribute__((ext_vector_type(8))) short short8v;
typedef __attribute__((ext_vector_type(4))) float f32x4;

// ---------------- bf16 helpers ----------------
__device__ __forceinline__ u16 f2bf(float f) {
    u32 u = __float_as_uint(f);
    u32 r = (u + 0x7fffu + ((u >> 16) & 1u)) >> 16;
    return (u16)r;
}
__device__ __forceinline__ float bff(u16 h) {
    return __uint_as_float(((u32)h) << 16);
}
__device__ __forceinline__ short8v cvt8(float4 u0, float4 u1) {
    union { u32 w[4]; short8v v; } r;
    r.w[0] = (u32)f2bf(u0.x) | ((u32)f2bf(u0.y) << 16);
    r.w[1] = (u32)f2bf(u0.z) | ((u32)f2bf(u0.w) << 16);
    r.w[2] = (u32)f2bf(u1.x) | ((u32)f2bf(u1.y) << 16);
    r.w[3] = (u32)f2bf(u1.z) | ((u32)f2bf(u1.w) << 16);
    return r.v;
}

// leaky_relu + batchnorm affine from raw sums
__device__ __forceinline__ float bnleaky(float v, float s, float q) {
    const float invN = 1.0f / 65536.0f;
    float mu = s * invN;
    float var = q * invN - mu * mu;
    float u = v >= 0.f ? v : 0.01f * v;
    return (u - mu) * rsqrtf(var + 1e-5f);
}
__device__ __forceinline__ void bn4(float4& u, float4 s, float4 q) {
    u.x = bnleaky(u.x, s.x, q.x);
    u.y = bnleaky(u.y, s.y, q.y);
    u.z = bnleaky(u.z, s.z, q.z);
    u.w = bnleaky(u.w, s.w, q.w);
}

// ---------------- threefry2x32 (JAX-compatible, key = (0,42)) ----------------
__device__ __forceinline__ u32 rotl32(u32 x, int d) {
    return (x << d) | (x >> (32 - d));
}
__device__ __forceinline__ void threefry_0_42(u32& x0, u32& x1) {
    const u32 ks0 = 0u, ks1 = 42u, ks2 = 0u ^ 42u ^ 0x1BD11BDAu;
    x0 += ks0; x1 += ks1;
#define RND(r) { x0 += x1; x1 = rotl32(x1, r); x1 ^= x0; }
    RND(13) RND(15) RND(26) RND(6)  x0 += ks1; x1 += ks2 + 1u;
    RND(17) RND(29) RND(16) RND(24) x0 += ks2; x1 += ks0 + 2u;
    RND(13) RND(15) RND(26) RND(6)  x0 += ks0; x1 += ks1 + 3u;
    RND(17) RND(29) RND(16) RND(24) x0 += ks1; x1 += ks2 + 4u;
    RND(13) RND(15) RND(26) RND(6)  x0 += ks2; x1 += ks0 + 5u;
#undef RND
}

// ---------------- graph preprocessing ----------------
__global__ void k_indeg(const int* __restrict__ dst, int* __restrict__ indeg) {
    int e = blockIdx.x * 256 + threadIdx.x;
    if (e < EE) atomicAdd(&indeg[dst[e]], 1);
}

__global__ void k_scan(const int* __restrict__ indeg, int* __restrict__ rowptr,
                       int* __restrict__ cursor) {
    __shared__ int psum[256];
    int t = threadIdx.x;
    int base = t * 256;
    int s = 0;
    for (int i = 0; i < 256; ++i) s += indeg[base + i];
    psum[t] = s;
    __syncthreads();
    for (int off = 1; off < 256; off <<= 1) {
        int v = (t >= off) ? psum[t - off] : 0;
        __syncthreads();
        psum[t] += v;
        __syncthreads();
    }
    int run = (t == 0) ? 0 : psum[t - 1];
    for (int i = 0; i < 256; ++i) {
        rowptr[base + i] = run;
        cursor[base + i] = run;
        run += indeg[base + i];
    }
    if (t == 255) rowptr[NN] = run;
}

__global__ void k_fill(const int* __restrict__ src, const int* __restrict__ dst,
                       int* __restrict__ cursor, int* __restrict__ csr) {
    int e = blockIdx.x * 256 + threadIdx.x;
    if (e < EE) {
        int d = dst[e];
        int p = atomicAdd(&cursor[d], 1);
        csr[p] = src[e];
    }
}

__global__ void k_dinv(const int* __restrict__ indeg, float* __restrict__ dinv) {
    int i = blockIdx.x * 256 + threadIdx.x;
    if (i < NN) dinv[i] = rsqrtf((float)indeg[i] + 1.0f);
}

// ---------------- stacked weight transpose + hi/lo bf16 split ----------------
// rows [0,CS): Wr (out1 cols); rows [CS,NPW): Wl (out2 cols) or zero
__global__ void k_wsplit2(const float* __restrict__ Wr, const float* __restrict__ Wlsrc,
                          int K, int N, int KP, int CS, int NPW,
                          u16* __restrict__ Wh, u16* __restrict__ Wl) {
    int idx = blockIdx.x * 256 + threadIdx.x;
    if (idx >= NPW * KP) return;
    int n = idx / KP, k = idx % KP;
    float v = 0.f;
    if (n < CS) {
        if (n < N && k < K) v = Wr[(size_t)k * N + n];
    } else {
        int n2 = n - CS;
        if (Wlsrc != nullptr && n2 < N && k < K) v = Wlsrc[(size_t)k * N + n2];
    }
    u16 h = f2bf(v);
    u16 l = f2bf(v - bff(h));
    Wh[idx] = h;
    Wl[idx] = l;
}

// ---------------- direct-global MFMA GEMM: no LDS, no barriers ----------------
// Wave owns 32 rows x 64 cols; block = 4 waves stacked in M (128 rows).
// grid = (stackedN/64, M/128). A fp32 read direct (1 cache line per row per
// K-step, converted to bf16-hi in-register, BN+leaky fused); W hi/lo read
// direct from pre-transposed [n][k] bf16 (L2-resident).
// O1[M x CS] = bn(A) @ W[rows 0..CS)  (+bias for col<N)
// O2[M x CS] = bn(A) @ W[rows CS..2CS)   (if tile lands there)
template <bool HASB, bool HASBN>
__global__ __launch_bounds__(256, 4) void k_gemm_direct(
    const float* __restrict__ A, const u16* __restrict__ Wgh, const u16* __restrict__ Wgl,
    int KP, int lda, const float* __restrict__ bns,
    const float* __restrict__ bias, float* __restrict__ O1, float* __restrict__ O2,
    int N, int CS) {
    const int t = threadIdx.x;
    const int lane = t & 63;
    const int wid = t >> 6;
    const int bm = blockIdx.y * 128 + wid * 32;
    const int bn = blockIdx.x * 64;
    const int fr = lane & 15;
    const int kg = (lane >> 4) * 8;

    f32x4 acc[2][4];
#pragma unroll
    for (int m = 0; m < 2; ++m)
#pragma unroll
        for (int n = 0; n < 4; ++n) acc[m][n] = (f32x4){0.f, 0.f, 0.f, 0.f};

    const float* a0p = A + (size_t)(bm + fr) * lda + kg;
    const float* a1p = A + (size_t)(bm + 16 + fr) * lda + kg;
    const u16* whp[4];
    const u16* wlp[4];
#pragma unroll
    for (int n = 0; n < 4; ++n) {
        size_t o = (size_t)(bn + n * 16 + fr) * KP + kg;
        whp[n] = Wgh + o;
        wlp[n] = Wgl + o;
    }

    for (int k0 = 0; k0 < KP; k0 += 32) {
        float4 u00 = *(const float4*)(a0p + k0);
        float4 u01 = *(const float4*)(a0p + k0 + 4);
        float4 u10 = *(const float4*)(a1p + k0);
        float4 u11 = *(const float4*)(a1p + k0 + 4);
        if (HASBN) {
            float4 s0 = *(const float4*)(bns + k0 + kg);
            float4 s1 = *(const float4*)(bns + k0 + kg + 4);
            float4 q0 = *(const float4*)(bns + 512 + k0 + kg);
            float4 q1 = *(const float4*)(bns + 512 + k0 + kg + 4);
            bn4(u00, s0, q0); bn4(u01, s1, q1);
            bn4(u10, s0, q0); bn4(u11, s1, q1);
        }
        short8v ah0 = cvt8(u00, u01);
        short8v ah1 = cvt8(u10, u11);
#pragma unroll
        for (int n = 0; n < 4; ++n) {
            short8v wh = *(const short8v*)(whp[n] + k0);
            short8v wl = *(const short8v*)(wlp[n] + k0);
            acc[0][n] = __builtin_amdgcn_mfma_f32_16x16x32_bf16(ah0, wh, acc[0][n], 0, 0, 0);
            acc[1][n] = __builtin_amdgcn_mfma_f32_16x16x32_bf16(ah1, wh, acc[1][n], 0, 0, 0);
            acc[0][n] = __builtin_amdgcn_mfma_f32_16x16x32_bf16(ah0, wl, acc[0][n], 0, 0, 0);
            acc[1][n] = __builtin_amdgcn_mfma_f32_16x16x32_bf16(ah1, wl, acc[1][n], 0, 0, 0);
        }
    }

    // epilogue: C/D frag col = lane&15, row = (lane>>4)*4 + e
    float* O = O1;
    int colb = bn;
    bool isO1 = true;
    if (bn >= CS) { O = O2; colb = bn - CS; isO1 = false; }
    const int fq = lane >> 4;
#pragma unroll
    for (int m = 0; m < 2; ++m) {
        int row = bm + m * 16 + fq * 4;
#pragma unroll
        for (int n = 0; n < 4; ++n) {
            int gcol = bn + n * 16 + fr;
            int col = colb + n * 16 + fr;
            float b = 0.f;
            if (HASB && isO1 && gcol < N) b = bias[gcol];
#pragma unroll
            for (int e = 0; e < 4; ++e)
                O[(size_t)(row + e) * CS + col] = acc[m][n][e] + b;
        }
    }
}

// ---------------- GCN aggregation, D=320 (float4, edge unroll-4) ----------------
__global__ __launch_bounds__(256) void k_gcn_agg320(const float* __restrict__ h,
                                                    const int* __restrict__ rowptr,
                                                    const int* __restrict__ csr,
                                                    const float* __restrict__ dinv,
                                                    const float* __restrict__ bias,
                                                    float* __restrict__ out) {
    int lane = threadIdx.x & 63;
    int n = blockIdx.x * 4 + (threadIdx.x >> 6);
    bool has1 = lane < 16;
    float di = dinv[n];
    float s2 = di * di;
    const float4* hn = (const float4*)(h + (size_t)n * 320);
    float4 v0 = hn[lane];
    float4 a0 = make_float4(v0.x * s2, v0.y * s2, v0.z * s2, v0.w * s2);
    float4 a1 = make_float4(0.f, 0.f, 0.f, 0.f);
    if (has1) {
        float4 v1 = hn[64 + lane];
        a1 = make_float4(v1.x * s2, v1.y * s2, v1.z * s2, v1.w * s2);
    }
    int e = rowptr[n], e1 = rowptr[n + 1];
    for (; e + 4 <= e1; e += 4) {
        int s0 = csr[e], s1 = csr[e + 1], s2i = csr[e + 2], s3 = csr[e + 3];
        float w0 = dinv[s0] * di, w1 = dinv[s1] * di, w2 = dinv[s2i] * di, w3 = dinv[s3] * di;
        const float4* p0 = (const float4*)(h + (size_t)s0 * 320);
        const float4* p1 = (const float4*)(h + (size_t)s1 * 320);
        const float4* p2 = (const float4*)(h + (size_t)s2i * 320);
        const float4* p3 = (const float4*)(h + (size_t)s3 * 320);
        float4 u0 = p0[lane], u1 = p1[lane], u2 = p2[lane], u3 = p3[lane];
        a0.x += u0.x * w0 + u1.x * w1 + u2.x * w2 + u3.x * w3;
        a0.y += u0.y * w0 + u1.y * w1 + u2.y * w2 + u3.y * w3;
        a0.z += u0.z * w0 + u1.z * w1 + u2.z * w2 + u3.z * w3;
        a0.w += u0.w * w0 + u1.w * w1 + u2.w * w2 + u3.w * w3;
        if (has1) {
            float4 x0 = p0[64 + lane], x1 = p1[64 + lane], x2 = p2[64 + lane], x3 = p3[64 + lane];
            a1.x += x0.x * w0 + x1.x * w1 + x2.x * w2 + x3.x * w3;
            a1.y += x0.y * w0 + x1.y * w1 + x2.y * w2 + x3.y * w3;
            a1.z += x0.z * w0 + x1.z * w1 + x2.z * w2 + x3.z * w3;
            a1.w += x0.w * w0 + x1.w * w1 + x2.w * w2 + x3.w * w3;
        }
    }
    for (; e < e1; ++e) {
        int s = csr[e];
        float w = dinv[s] * di;
        const float4* hs = (const float4*)(h + (size_t)s * 320);
        float4 u0 = hs[lane];
        a0.x = fmaf(u0.x, w, a0.x); a0.y = fmaf(u0.y, w, a0.y);
        a0.z = fmaf(u0.z, w, a0.z); a0.w = fmaf(u0.w, w, a0.w);
        if (has1) {
            float4 u1 = hs[64 + lane];
            a1.x = fmaf(u1.x, w, a1.x); a1.y = fmaf(u1.y, w, a1.y);
            a1.z = fmaf(u1.z, w, a1.z); a1.w = fmaf(u1.w, w, a1.w);
        }
    }
    const float4* b4 = (const float4*)bias;
    float4* on = (float4*)(out + (size_t)n * 320);
    float4 bb = b4[lane];
    on[lane] = make_float4(a0.x + bb.x, a0.y + bb.y, a0.z + bb.z, a0.w + bb.w);
    if (has1) {
        float4 bb1 = b4[64 + lane];
        on[64 + lane] = make_float4(a1.x + bb1.x, a1.y + bb1.y, a1.z + bb1.z, a1.w + bb1.w);
    }
}

// ---------------- C[n] += mean-gather(T[s]); stride = 4*CH floats ----------------
template <int CH, int LOG_NPW>
__global__ __launch_bounds__(256) void k_agg_add(const float* __restrict__ T,
                                                 const int* __restrict__ rowptr,
                                                 const int* __restrict__ csr,
                                                 const int* __restrict__ indeg,
                                                 float* __restrict__ C) {
    constexpr int NPW = 1 << LOG_NPW;
    constexpr int LPN = 64 >> LOG_NPW;
    constexpr int SC = CH * 4;
    int lane = threadIdx.x & 63;
    int sub = lane / LPN;
    int ch = lane & (LPN - 1);
    int n = (blockIdx.x * 4 + (threadIdx.x >> 6)) * NPW + sub;
    bool act = ch < CH;
    float4 acc = make_float4(0.f, 0.f, 0.f, 0.f);
    int e = rowptr[n], e1 = rowptr[n + 1];
    for (; e + 4 <= e1; e += 4) {
        int s0 = csr[e], s1 = csr[e + 1], s2 = csr[e + 2], s3 = csr[e + 3];
        if (act) {
            float4 u0 = *(const float4*)(T + (size_t)s0 * SC + ch * 4);
            float4 u1 = *(const float4*)(T + (size_t)s1 * SC + ch * 4);
            float4 u2 = *(const float4*)(T + (size_t)s2 * SC + ch * 4);
            float4 u3 = *(const float4*)(T + (size_t)s3 * SC + ch * 4);
            acc.x += (u0.x + u1.x) + (u2.x + u3.x);
            acc.y += (u0.y + u1.y) + (u2.y + u3.y);
            acc.z += (u0.z + u1.z) + (u2.z + u3.z);
            acc.w += (u0.w + u1.w) + (u2.w + u3.w);
        }
    }
    for (; e < e1; ++e) {
        int s = csr[e];
        if (act) {
            float4 u = *(const float4*)(T + (size_t)s * SC + ch * 4);
            acc.x += u.x; acc.y += u.y; acc.z += u.z; acc.w += u.w;
        }
    }
    int cnt = indeg[n];
    float inv = 1.0f / (float)(cnt > 1 ? cnt : 1);
    if (act) {
        float4* cp = (float4*)(C + (size_t)n * SC + ch * 4);
        float4 c = *cp;
        c.x = fmaf(acc.x, inv, c.x);
        c.y = fmaf(acc.y, inv, c.y);
        c.z = fmaf(acc.z, inv, c.z);
        c.w = fmaf(acc.w, inv, c.w);
        *cp = c;
    }
}

// ---------------- batchnorm stats (leaky fused); 1024 blocks x 64 rows ----------------
template <int D, int STR>
__global__ __launch_bounds__(256) void k_bn_stats(const float* __restrict__ x,
                                                  float* __restrict__ stats) {
    constexpr int NC = (D + 255) / 256;
    int t = threadIdx.x;
    int r0 = blockIdx.x * 64;
    float s[NC], q[NC];
#pragma unroll
    for (int i = 0; i < NC; ++i) { s[i] = 0.f; q[i] = 0.f; }
#pragma unroll 4
    for (int r = r0; r < r0 + 64; ++r) {
        const float* row = x + (size_t)r * STR;
#pragma unroll
        for (int i = 0; i < NC; ++i) {
            int c = t + 256 * i;
            if (c < D) {
                float v = row[c];
                v = v >= 0.f ? v : 0.01f * v;
                s[i] += v;
                q[i] += v * v;
            }
        }
    }
#pragma unroll
    for (int i = 0; i < NC; ++i) {
        int c = t + 256 * i;
        if (c < D) {
            atomicAdd(&stats[c], s[i]);
            atomicAdd(&stats[512 + c], q[i]);
        }
    }
}

template <int STR>
__global__ __launch_bounds__(256) void k_bn_apply(float* __restrict__ x,
                                                  const float* __restrict__ stats) {
    size_t total4 = (size_t)NN * STR / 4;
    size_t stride = (size_t)gridDim.x * 256;
    for (size_t i = (size_t)blockIdx.x * 256 + threadIdx.x; i < total4; i += stride) {
        int c = (int)((i * 4) % STR);
        float4 v = ((const float4*)x)[i];
        float4 m4 = *(const float4*)(stats + c);
        float4 q4 = *(const float4*)(stats + 512 + c);
        float4 o;
        o.x = bnleaky(v.x, m4.x, q4.x);
        o.y = bnleaky(v.y, m4.y, q4.y);
        o.z = bnleaky(v.z, m4.z, q4.z);
        o.w = bnleaky(v.w, m4.w, q4.w);
        ((float4*)x)[i] = o;
    }
}

// ---------------- pooling (input stride 64) ----------------
__global__ __launch_bounds__(256) void k_pool(const float* __restrict__ h,
                                              float* __restrict__ pooled) {
    int blk = blockIdx.x;
    int batch = blk >> 4, seg = blk & 15;
    int f = threadIdx.x & 63, g = threadIdx.x >> 6;
    size_t base = ((size_t)batch * 4096 + seg * 256 + g) * 64 + f;
    float acc = 0.f;
    for (int i = 0; i < 64; ++i) acc += h[base + (size_t)i * 256];
    atomicAdd(&pooled[batch * 64 + f], acc);
}

// ---------------- head ----------------
__global__ __launch_bounds__(256) void k_head(
    const float* __restrict__ gender, const float* __restrict__ age,
    const float* __restrict__ handed, const float* __restrict__ Wq,
    const float* __restrict__ bq, const float* __restrict__ Wk,
    const float* __restrict__ bk, const float* __restrict__ Wv,
    const float* __restrict__ bv, const float* __restrict__ Wfc,
    const float* __restrict__ bfc, const float* __restrict__ Wf1,
    const float* __restrict__ bf1, const float* __restrict__ Wf2,
    const float* __restrict__ bf2, const float* __restrict__ Wf3,
    const float* __restrict__ bf3, const float* __restrict__ pooled,
    float* __restrict__ dout) {
    __shared__ float plug[BS_][8];
    __shared__ float qs[BS_][32], ks[BS_][32], vs[BS_][32];
    __shared__ float gum[256];
    __shared__ float x32[BS_][32];
    __shared__ float px[BS_][4];
    __shared__ float embs[BS_][54];
    __shared__ float t1[BS_][32];
    __shared__ float t2[BS_][16];
    int t = threadIdx.x;

    if (t < 128) {
        int b = t >> 3, c = t & 7;
        float v;
        if (c < 2) v = gender[b * 2 + c];
        else if (c == 2) v = age[b];
        else v = handed[b * 5 + (c - 3)];
        plug[b][c] = v;
    }
    {
        u32 lane = (u32)(t & 127);
        u32 a = lane, b2 = lane + 128u;
        threefry_0_42(a, b2);
        u32 bits = (t < 128) ? a : b2;
        float u = __uint_as_float((bits >> 9) | 0x3f800000u) - 1.0f;
        const float mn = 1e-9f;
        u = u * (1.0f - mn) + mn;
        u = fmaxf(mn, u);
        gum[t] = -logf(-logf(u));
    }
    __syncthreads();
    for (int idx = t; idx < 512; idx += 256) {
        int b = idx >> 5, c = idx & 31;
        float aq = bq[c], ak = bk[c], av = bv[c];
#pragma unroll
        for (int i = 0; i < 8; ++i) {
            float p = plug[b][i];
            aq = fmaf(p, Wq[i * 32 + c], aq);
            ak = fmaf(p, Wk[i * 32 + c], ak);
            av = fmaf(p, Wv[i * 32 + c], av);
        }
        qs[b][c] = aq; ks[b][c] = ak; vs[b][c] = av;
    }
    __syncthreads();
    if (t < 64) {
        int b = t >> 2, h = t & 3;
        const float isq = 0.35355339059327373f;
        const float sq = 2.8284271247461903f;
        float sc[4];
#pragma unroll
        for (int j = 0; j < 4; ++j) {
            float d = 0.f;
#pragma unroll
            for (int dd = 0; dd < 8; ++dd) d = fmaf(qs[b][h * 8 + dd], ks[b][j * 8 + dd], d);
            sc[j] = d * isq + gum[b * 16 + h * 4 + j];
        }
        float m = fmaxf(fmaxf(sc[0], sc[1]), fmaxf(sc[2], sc[3]));
        float e0 = expf(sc[0] - m), e1 = expf(sc[1] - m), e2 = expf(sc[2] - m), e3 = expf(sc[3] - m);
        float sum = e0 + e1 + e2 + e3;
        float a0 = e0 / sum * sq, a1 = e1 / sum * sq, a2 = e2 / sum * sq, a3 = e3 / sum * sq;
#pragma unroll
        for (int dd = 0; dd < 8; ++dd) {
            float o = a0 * vs[b][0 * 8 + dd] + a1 * vs[b][1 * 8 + dd] +
                      a2 * vs[b][2 * 8 + dd] + a3 * vs[b][3 * 8 + dd];
            x32[b][h * 8 + dd] = o;
        }
    }
    __syncthreads();
    if (t < 64) {
        int b = t >> 2, n = t & 3;
        float a = bfc[n];
#pragma unroll
        for (int m = 0; m < 32; ++m) a = fmaf(x32[b][m], Wfc[m * 4 + n], a);
        px[b][n] = a;
    }
    __syncthreads();
    for (int idx = t; idx < BS_ * 54; idx += 256) {
        int b = idx / 54, c = idx % 54;
        float v = (c < 50) ? pooled[b * 64 + c] : px[b][c - 50];
        embs[b][c] = v;
        dout[16 + idx] = v;
    }
    __syncthreads();
    for (int idx = t; idx < 512; idx += 256) {
        int b = idx >> 5, c = idx & 31;
        float a = bf1[c];
#pragma unroll
        for (int k = 0; k < 54; ++k) a = fmaf(embs[b][k], Wf1[k * 32 + c], a);
        t1[b][c] = a;
    }
    __syncthreads();
    {
        int b = t >> 4, c = t & 15;
        float a = bf2[c];
#pragma unroll
        for (int k = 0; k < 32; ++k) a = fmaf(t1[b][k], Wf2[k * 16 + c], a);
        t2[b][c] = a;
    }
    __syncthreads();
    if (t < 16) {
        float a = bf3[0];
#pragma unroll
        for (int k = 0; k < 16; ++k) a = fmaf(t2[t][k], Wf3[k], a);
        dout[t] = a;
    }
}

// ---------------- launcher ----------------
extern "C" void kernel_launch(void* const* d_in, const int* in_sizes, int n_in,
                              void* d_out, int out_size, void* d_ws, size_t ws_size,
                              hipStream_t stream) {
    const float* x      = (const float*)d_in[0];
    const int*   ei     = (const int*)d_in[1];
    const float* gender = (const float*)d_in[2];
    const float* age    = (const float*)d_in[3];
    const float* handed = (const float*)d_in[4];
    const float* W1  = (const float*)d_in[5];
    const float* b1  = (const float*)d_in[6];
    const float* Wl2 = (const float*)d_in[7];
    const float* Wr2 = (const float*)d_in[8];
    const float* b2  = (const float*)d_in[9];
    const float* Wl3 = (const float*)d_in[10];
    const float* Wr3 = (const float*)d_in[11];
    const float* b3  = (const float*)d_in[12];
    const float* Wl4 = (const float*)d_in[13];
    const float* Wr4 = (const float*)d_in[14];
    const float* b4  = (const float*)d_in[15];
    const float* Wq  = (const float*)d_in[16];
    const float* bq  = (const float*)d_in[17];
    const float* Wk  = (const float*)d_in[18];
    const float* bk  = (const float*)d_in[19];
    const float* Wv  = (const float*)d_in[20];
    const float* bv  = (const float*)d_in[21];
    const float* Wfc = (const float*)d_in[22];
    const float* bfc = (const float*)d_in[23];
    const float* Wf1 = (const float*)d_in[24];
    const float* bf1 = (const float*)d_in[25];
    const float* Wf2 = (const float*)d_in[26];
    const float* bf2 = (const float*)d_in[27];
    const float* Wf3 = (const float*)d_in[28];
    const float* bf3 = (const float*)d_in[29];

    const int* srcp = ei;
    const int* dstp = ei + EE;

    char* wsb = (char*)d_ws;
    size_t off = 0;
    auto alloc = [&](size_t bytes) -> char* {
        char* p = wsb + off;
        off += (bytes + 255) & ~(size_t)255;
        return p;
    };
    float* P = (float*)alloc((size_t)NN * 320 * 4);
    float* Q = (float*)alloc((size_t)NN * 320 * 4);
    float* R = (float*)alloc((size_t)NN * 192 * 4);
    float* T = (float*)alloc((size_t)NN * 192 * 4);
    int* indeg  = (int*)alloc((size_t)NN * 4);
    int* rowptr = (int*)alloc((size_t)(NN + 1) * 4);
    int* cursor = (int*)alloc((size_t)(NN + 1) * 4);
    int* csr    = (int*)alloc((size_t)EE * 4);
    float* dinv = (float*)alloc((size_t)NN * 4);
    float* stats  = (float*)alloc(4096 * 4);  // 4 regions x 1024
    float* pooled = (float*)alloc(16 * 64 * 4);
    // stacked weight splits: [NPW][KP] bf16 hi/lo
    u16* W1h = (u16*)alloc((size_t)384 * 640 * 2);
    u16* W1l = (u16*)alloc((size_t)384 * 640 * 2);
    u16* W2h = (u16*)alloc((size_t)384 * 320 * 2);
    u16* W2l = (u16*)alloc((size_t)384 * 320 * 2);
    u16* W3h = (u16*)alloc((size_t)256 * 192 * 2);
    u16* W3l = (u16*)alloc((size_t)256 * 192 * 2);
    u16* W4h = (u16*)alloc((size_t)128 * 128 * 2);
    u16* W4l = (u16*)alloc((size_t)128 * 128 * 2);
    float* dout = (float*)d_out;

    // graph preprocessing
    hipMemsetAsync(indeg, 0, (size_t)NN * 4, stream);
    hipMemsetAsync(stats, 0, 4096 * 4, stream);
    k_indeg<<<EE / 256, 256, 0, stream>>>(dstp, indeg);
    k_scan<<<1, 256, 0, stream>>>(indeg, rowptr, cursor);
    k_fill<<<EE / 256, 256, 0, stream>>>(srcp, dstp, cursor, csr);
    k_dinv<<<NN / 256, 256, 0, stream>>>(indeg, dinv);

    // weight splits (stacked [Wr | Wl])
    k_wsplit2<<<(384 * 640 + 255) / 256, 256, 0, stream>>>(W1, nullptr, 640, 320, 640, 320, 384, W1h, W1l);
    k_wsplit2<<<(384 * 320 + 255) / 256, 256, 0, stream>>>(Wr2, Wl2, 320, 180, 320, 192, 384, W2h, W2l);
    k_wsplit2<<<(256 * 192 + 255) / 256, 256, 0, stream>>>(Wr3, Wl3, 180, 90, 192, 128, 256, W3h, W3l);
    k_wsplit2<<<(128 * 128 + 255) / 256, 256, 0, stream>>>(Wr4, Wl4, 90, 50, 128, 64, 128, W4h, W4l);

    // layer 1: GCN (640 -> 320).  P = x @ W1 ; Q = gcn_agg(P) + b1 (raw, pre-BN)
    k_gemm_direct<false, false><<<dim3(5, 512), 256, 0, stream>>>(
        x, W1h, W1l, 640, 640, nullptr, nullptr, P, nullptr, 320, 320);
    k_gcn_agg320<<<NN / 4, 256, 0, stream>>>(P, rowptr, csr, dinv, b1, Q);
    k_bn_stats<320, 320><<<1024, 256, 0, stream>>>(Q, stats);

    // layer 2: SAGE (320 -> 180, stride 192).  [R | T] = bn(Q) @ [Wr2 | Wl2]; R += mean(T)
    k_gemm_direct<true, true><<<dim3(6, 512), 256, 0, stream>>>(
        Q, W2h, W2l, 320, 320, stats, b2, R, T, 180, 192);
    k_agg_add<48, 0><<<NN / 4, 256, 0, stream>>>(T, rowptr, csr, indeg, R);
    k_bn_stats<180, 192><<<1024, 256, 0, stream>>>(R, stats + 1024);

    // layer 3: SAGE (180 -> 90, stride 128).  [P | T] = bn(R) @ [Wr3 | Wl3]; P += mean(T)
    k_gemm_direct<true, true><<<dim3(4, 512), 256, 0, stream>>>(
        R, W3h, W3l, 192, 192, stats + 1024, b3, P, T, 90, 128);
    k_agg_add<32, 1><<<NN / 8, 256, 0, stream>>>(T, rowptr, csr, indeg, P);
    k_bn_stats<90, 128><<<1024, 256, 0, stream>>>(P, stats + 2048);

    // layer 4: SAGE (90 -> 50, stride 64).  [Q | T] = bn(P) @ [Wr4 | Wl4]; Q += mean(T)
    k_gemm_direct<true, true><<<dim3(2, 512), 256, 0, stream>>>(
        P, W4h, W4l, 128, 128, stats + 2048, b4, Q, T, 50, 64);
    k_agg_add<16, 2><<<NN / 16, 256, 0, stream>>>(T, rowptr, csr, indeg, Q);
    k_bn_stats<50, 64><<<1024, 256, 0, stream>>>(Q, stats + 3072);
    k_bn_apply<64><<<2048, 256, 0, stream>>>(Q, stats + 3072);

    // pooling + head
    hipMemsetAsync(pooled, 0, 16 * 64 * 4, stream);
    k_pool<<<256, 256, 0, stream>>>(Q, pooled);
    k_head<<<1, 256, 0, stream>>>(gender, age, handed, Wq, bq, Wk, bk, Wv, bv,
                                  Wfc, bfc, Wf1, bf1, Wf2, bf2, Wf3, bf3, pooled, dout);
}

// Round 9
// 1050.401 us; speedup vs baseline: 1.3256x; 1.3256x over previous
//
#include <hip/hip_runtime.h>
#include <cstdint>

#define NN 65536
#define EE 524288
#define BS_ 16

typedef unsigned short u16;
typedef unsigned int u32;
typedef __attribute__((ext_vector_type(8))) short short8v;
typedef __attribute__((ext_vector_type(4))) float f32x4;

// ---------------- bf16 helpers ----------------
__device__ __forceinline__ u16 f2bf(float f) {
    u32 u = __float_as_uint(f);
    u32 r = (u + 0x7fffu + ((u >> 16) & 1u)) >> 16;
    return (u16)r;
}
__device__ __forceinline__ float bff(u16 h) {
    return __uint_as_float(((u32)h) << 16);
}

// leaky_relu + batchnorm affine from raw sums
__device__ __forceinline__ float bnleaky(float v, float s, float q) {
    const float invN = 1.0f / 65536.0f;
    float mu = s * invN;
    float var = q * invN - mu * mu;
    float u = v >= 0.f ? v : 0.01f * v;
    return (u - mu) * rsqrtf(var + 1e-5f);
}

// ---------------- threefry2x32 (JAX-compatible, key = (0,42)) ----------------
__device__ __forceinline__ u32 rotl32(u32 x, int d) {
    return (x << d) | (x >> (32 - d));
}
__device__ __forceinline__ void threefry_0_42(u32& x0, u32& x1) {
    const u32 ks0 = 0u, ks1 = 42u, ks2 = 0u ^ 42u ^ 0x1BD11BDAu;
    x0 += ks0; x1 += ks1;
#define RND(r) { x0 += x1; x1 = rotl32(x1, r); x1 ^= x0; }
    RND(13) RND(15) RND(26) RND(6)  x0 += ks1; x1 += ks2 + 1u;
    RND(17) RND(29) RND(16) RND(24) x0 += ks2; x1 += ks0 + 2u;
    RND(13) RND(15) RND(26) RND(6)  x0 += ks0; x1 += ks1 + 3u;
    RND(17) RND(29) RND(16) RND(24) x0 += ks1; x1 += ks2 + 4u;
    RND(13) RND(15) RND(26) RND(6)  x0 += ks2; x1 += ks0 + 5u;
#undef RND
}

// ---------------- graph preprocessing ----------------
__global__ void k_indeg(const int* __restrict__ dst, int* __restrict__ indeg) {
    int e = blockIdx.x * 256 + threadIdx.x;
    if (e < EE) atomicAdd(&indeg[dst[e]], 1);
}

__global__ void k_scan(const int* __restrict__ indeg, int* __restrict__ rowptr,
                       int* __restrict__ cursor) {
    __shared__ int psum[256];
    int t = threadIdx.x;
    int base = t * 256;
    int s = 0;
    for (int i = 0; i < 256; ++i) s += indeg[base + i];
    psum[t] = s;
    __syncthreads();
    for (int off = 1; off < 256; off <<= 1) {
        int v = (t >= off) ? psum[t - off] : 0;
        __syncthreads();
        psum[t] += v;
        __syncthreads();
    }
    int run = (t == 0) ? 0 : psum[t - 1];
    for (int i = 0; i < 256; ++i) {
        rowptr[base + i] = run;
        cursor[base + i] = run;
        run += indeg[base + i];
    }
    if (t == 255) rowptr[NN] = run;
}

__global__ void k_fill(const int* __restrict__ src, const int* __restrict__ dst,
                       int* __restrict__ cursor, int* __restrict__ csr) {
    int e = blockIdx.x * 256 + threadIdx.x;
    if (e < EE) {
        int d = dst[e];
        int p = atomicAdd(&cursor[d], 1);
        csr[p] = src[e];
    }
}

__global__ void k_dinv(const int* __restrict__ indeg, float* __restrict__ dinv) {
    int i = blockIdx.x * 256 + threadIdx.x;
    if (i < NN) dinv[i] = rsqrtf((float)indeg[i] + 1.0f);
}

// ---------------- stacked weight transpose + hi/lo bf16 split ----------------
// rows [0,CS): Wr (out1 cols); rows [CS,NPW): Wl (out2 cols) or zero
__global__ void k_wsplit2(const float* __restrict__ Wr, const float* __restrict__ Wlsrc,
                          int K, int N, int KP, int CS, int NPW,
                          u16* __restrict__ Wh, u16* __restrict__ Wl) {
    int idx = blockIdx.x * 256 + threadIdx.x;
    if (idx >= NPW * KP) return;
    int n = idx / KP, k = idx % KP;
    float v = 0.f;
    if (n < CS) {
        if (n < N && k < K) v = Wr[(size_t)k * N + n];
    } else {
        int n2 = n - CS;
        if (Wlsrc != nullptr && n2 < N && k < K) v = Wlsrc[(size_t)k * N + n2];
    }
    u16 h = f2bf(v);
    u16 l = f2bf(v - bff(h));
    Wh[idx] = h;
    Wl[idx] = l;
}

// ---------------- bf16 MFMA GEMM: A-hi x (W-hi + W-lo), 2-phase LDS ----------------
// Block 64 rows x 128 cols, 4 waves (2x2); grid dim3(M/64, NT) M-fastest.
// O1[M x CS] = bn(A) @ W[rows 0..CS)  (+bias for col<N)
// O2[M x CS] = bn(A) @ W[rows CS..2CS)   (if O2 != null)
template <bool HASB, bool HASBN>
__global__ __launch_bounds__(256, 3) void k_gemm_mfma(
    const float* __restrict__ A, const u16* __restrict__ Wgh, const u16* __restrict__ Wgl,
    int KP, int lda, const float* __restrict__ bns,
    const float* __restrict__ bias, float* __restrict__ O1, float* __restrict__ O2,
    int N, int CS) {
    __shared__ u16 Ah[64][72];
    __shared__ u16 Wh[128][72];
    __shared__ u16 Wl[128][72];

    const int t = threadIdx.x;
    const int bm = blockIdx.x * 64;
    const int bn = blockIdx.y * 128;
    const int lane = t & 63;
    const int wid = t >> 6;
    const int wr = wid >> 1, wc = wid & 1;

    f32x4 acc[2][4];
#pragma unroll
    for (int m = 0; m < 2; ++m)
#pragma unroll
        for (int n = 0; n < 4; ++n) acc[m][n] = (f32x4){0.f, 0.f, 0.f, 0.f};

    const int sr = t >> 4;
    const int sc4 = (t & 15) * 4;

    for (int k0 = 0; k0 < KP; k0 += 64) {
        float4 s4, q4;
        if (HASBN) {
            s4 = *(const float4*)(bns + k0 + sc4);
            q4 = *(const float4*)(bns + 512 + k0 + sc4);
        }
#pragma unroll
        for (int p = 0; p < 4; ++p) {
            int rr = sr + 16 * p;
            float4 v = *(const float4*)(A + (size_t)(bm + rr) * lda + k0 + sc4);
            if (HASBN) {
                v.x = bnleaky(v.x, s4.x, q4.x);
                v.y = bnleaky(v.y, s4.y, q4.y);
                v.z = bnleaky(v.z, s4.z, q4.z);
                v.w = bnleaky(v.w, s4.w, q4.w);
            }
            uint2 hh;
            hh.x = (u32)f2bf(v.x) | ((u32)f2bf(v.y) << 16);
            hh.y = (u32)f2bf(v.z) | ((u32)f2bf(v.w) << 16);
            *(uint2*)&Ah[rr][sc4] = hh;
        }
#pragma unroll
        for (int p = 0; p < 8; ++p) {
            int nn = sr + 16 * p;
            size_t go = (size_t)(bn + nn) * KP + k0 + sc4;
            *(uint2*)&Wh[nn][sc4] = *(const uint2*)(Wgh + go);
            *(uint2*)&Wl[nn][sc4] = *(const uint2*)(Wgl + go);
        }
        __syncthreads();
        const int fr = lane & 15;
        const int kg = (lane >> 4) * 8;
#pragma unroll
        for (int kk = 0; kk < 64; kk += 32) {
            short8v a_h[2], w_h[4], w_l[4];
#pragma unroll
            for (int m = 0; m < 2; ++m)
                a_h[m] = *(const short8v*)&Ah[wr * 32 + m * 16 + fr][kk + kg];
#pragma unroll
            for (int n = 0; n < 4; ++n) {
                w_h[n] = *(const short8v*)&Wh[wc * 64 + n * 16 + fr][kk + kg];
                w_l[n] = *(const short8v*)&Wl[wc * 64 + n * 16 + fr][kk + kg];
            }
#pragma unroll
            for (int m = 0; m < 2; ++m)
#pragma unroll
                for (int n = 0; n < 4; ++n) {
                    acc[m][n] = __builtin_amdgcn_mfma_f32_16x16x32_bf16(a_h[m], w_h[n], acc[m][n], 0, 0, 0);
                    acc[m][n] = __builtin_amdgcn_mfma_f32_16x16x32_bf16(a_h[m], w_l[n], acc[m][n], 0, 0, 0);
                }
        }
        __syncthreads();
    }
    const int fr = lane & 15, fq = lane >> 4;
#pragma unroll
    for (int m = 0; m < 2; ++m) {
        int row = bm + wr * 32 + m * 16 + fq * 4;
#pragma unroll
        for (int n = 0; n < 4; ++n) {
            int col = bn + wc * 64 + n * 16 + fr;
            if (col < CS) {
                float b = (HASB && col < N) ? bias[col] : 0.f;
#pragma unroll
                for (int e = 0; e < 4; ++e)
                    O1[(size_t)(row + e) * CS + col] = acc[m][n][e] + b;
            } else if (O2 != nullptr) {
                int c2 = col - CS;
#pragma unroll
                for (int e = 0; e < 4; ++e)
                    O2[(size_t)(row + e) * CS + c2] = acc[m][n][e];
            }
        }
    }
}

// ---------------- GCN aggregation, D=320 (float4, edge unroll-4) ----------------
__global__ __launch_bounds__(256) void k_gcn_agg320(const float* __restrict__ h,
                                                    const int* __restrict__ rowptr,
                                                    const int* __restrict__ csr,
                                                    const float* __restrict__ dinv,
                                                    const float* __restrict__ bias,
                                                    float* __restrict__ out) {
    int lane = threadIdx.x & 63;
    int n = blockIdx.x * 4 + (threadIdx.x >> 6);
    bool has1 = lane < 16;
    float di = dinv[n];
    float s2 = di * di;
    const float4* hn = (const float4*)(h + (size_t)n * 320);
    float4 v0 = hn[lane];
    float4 a0 = make_float4(v0.x * s2, v0.y * s2, v0.z * s2, v0.w * s2);
    float4 a1 = make_float4(0.f, 0.f, 0.f, 0.f);
    if (has1) {
        float4 v1 = hn[64 + lane];
        a1 = make_float4(v1.x * s2, v1.y * s2, v1.z * s2, v1.w * s2);
    }
    int e = rowptr[n], e1 = rowptr[n + 1];
    for (; e + 4 <= e1; e += 4) {
        int s0 = csr[e], s1 = csr[e + 1], s2i = csr[e + 2], s3 = csr[e + 3];
        float w0 = dinv[s0] * di, w1 = dinv[s1] * di, w2 = dinv[s2i] * di, w3 = dinv[s3] * di;
        const float4* p0 = (const float4*)(h + (size_t)s0 * 320);
        const float4* p1 = (const float4*)(h + (size_t)s1 * 320);
        const float4* p2 = (const float4*)(h + (size_t)s2i * 320);
        const float4* p3 = (const float4*)(h + (size_t)s3 * 320);
        float4 u0 = p0[lane], u1 = p1[lane], u2 = p2[lane], u3 = p3[lane];
        a0.x += u0.x * w0 + u1.x * w1 + u2.x * w2 + u3.x * w3;
        a0.y += u0.y * w0 + u1.y * w1 + u2.y * w2 + u3.y * w3;
        a0.z += u0.z * w0 + u1.z * w1 + u2.z * w2 + u3.z * w3;
        a0.w += u0.w * w0 + u1.w * w1 + u2.w * w2 + u3.w * w3;
        if (has1) {
            float4 x0 = p0[64 + lane], x1 = p1[64 + lane], x2 = p2[64 + lane], x3 = p3[64 + lane];
            a1.x += x0.x * w0 + x1.x * w1 + x2.x * w2 + x3.x * w3;
            a1.y += x0.y * w0 + x1.y * w1 + x2.y * w2 + x3.y * w3;
            a1.z += x0.z * w0 + x1.z * w1 + x2.z * w2 + x3.z * w3;
            a1.w += x0.w * w0 + x1.w * w1 + x2.w * w2 + x3.w * w3;
        }
    }
    for (; e < e1; ++e) {
        int s = csr[e];
        float w = dinv[s] * di;
        const float4* hs = (const float4*)(h + (size_t)s * 320);
        float4 u0 = hs[lane];
        a0.x = fmaf(u0.x, w, a0.x); a0.y = fmaf(u0.y, w, a0.y);
        a0.z = fmaf(u0.z, w, a0.z); a0.w = fmaf(u0.w, w, a0.w);
        if (has1) {
            float4 u1 = hs[64 + lane];
            a1.x = fmaf(u1.x, w, a1.x); a1.y = fmaf(u1.y, w, a1.y);
            a1.z = fmaf(u1.z, w, a1.z); a1.w = fmaf(u1.w, w, a1.w);
        }
    }
    const float4* b4 = (const float4*)bias;
    float4* on = (float4*)(out + (size_t)n * 320);
    float4 bb = b4[lane];
    on[lane] = make_float4(a0.x + bb.x, a0.y + bb.y, a0.z + bb.z, a0.w + bb.w);
    if (has1) {
        float4 bb1 = b4[64 + lane];
        on[64 + lane] = make_float4(a1.x + bb1.x, a1.y + bb1.y, a1.z + bb1.z, a1.w + bb1.w);
    }
}

// ---------------- C[n] += mean-gather(T[s]); stride = 4*CH floats ----------------
template <int CH, int LOG_NPW>
__global__ __launch_bounds__(256) void k_agg_add(const float* __restrict__ T,
                                                 const int* __restrict__ rowptr,
                                                 const int* __restrict__ csr,
                                                 const int* __restrict__ indeg,
                                                 float* __restrict__ C) {
    constexpr int NPW = 1 << LOG_NPW;
    constexpr int LPN = 64 >> LOG_NPW;
    constexpr int SC = CH * 4;
    int lane = threadIdx.x & 63;
    int sub = lane / LPN;
    int ch = lane & (LPN - 1);
    int n = (blockIdx.x * 4 + (threadIdx.x >> 6)) * NPW + sub;
    bool act = ch < CH;
    float4 acc = make_float4(0.f, 0.f, 0.f, 0.f);
    int e = rowptr[n], e1 = rowptr[n + 1];
    for (; e + 4 <= e1; e += 4) {
        int s0 = csr[e], s1 = csr[e + 1], s2 = csr[e + 2], s3 = csr[e + 3];
        if (act) {
            float4 u0 = *(const float4*)(T + (size_t)s0 * SC + ch * 4);
            float4 u1 = *(const float4*)(T + (size_t)s1 * SC + ch * 4);
            float4 u2 = *(const float4*)(T + (size_t)s2 * SC + ch * 4);
            float4 u3 = *(const float4*)(T + (size_t)s3 * SC + ch * 4);
            acc.x += (u0.x + u1.x) + (u2.x + u3.x);
            acc.y += (u0.y + u1.y) + (u2.y + u3.y);
            acc.z += (u0.z + u1.z) + (u2.z + u3.z);
            acc.w += (u0.w + u1.w) + (u2.w + u3.w);
        }
    }
    for (; e < e1; ++e) {
        int s = csr[e];
        if (act) {
            float4 u = *(const float4*)(T + (size_t)s * SC + ch * 4);
            acc.x += u.x; acc.y += u.y; acc.z += u.z; acc.w += u.w;
        }
    }
    int cnt = indeg[n];
    float inv = 1.0f / (float)(cnt > 1 ? cnt : 1);
    if (act) {
        float4* cp = (float4*)(C + (size_t)n * SC + ch * 4);
        float4 c = *cp;
        c.x = fmaf(acc.x, inv, c.x);
        c.y = fmaf(acc.y, inv, c.y);
        c.z = fmaf(acc.z, inv, c.z);
        c.w = fmaf(acc.w, inv, c.w);
        *cp = c;
    }
}

// ---------------- batchnorm stats (leaky fused); 1024 blocks x 64 rows ----------------
template <int D, int STR>
__global__ __launch_bounds__(256) void k_bn_stats(const float* __restrict__ x,
                                                  float* __restrict__ stats) {
    constexpr int NC = (D + 255) / 256;
    int t = threadIdx.x;
    int r0 = blockIdx.x * 64;
    float s[NC], q[NC];
#pragma unroll
    for (int i = 0; i < NC; ++i) { s[i] = 0.f; q[i] = 0.f; }
#pragma unroll 4
    for (int r = r0; r < r0 + 64; ++r) {
        const float* row = x + (size_t)r * STR;
#pragma unroll
        for (int i = 0; i < NC; ++i) {
            int c = t + 256 * i;
            if (c < D) {
                float v = row[c];
                v = v >= 0.f ? v : 0.01f * v;
                s[i] += v;
                q[i] += v * v;
            }
        }
    }
#pragma unroll
    for (int i = 0; i < NC; ++i) {
        int c = t + 256 * i;
        if (c < D) {
            atomicAdd(&stats[c], s[i]);
            atomicAdd(&stats[512 + c], q[i]);
        }
    }
}

template <int STR>
__global__ __launch_bounds__(256) void k_bn_apply(float* __restrict__ x,
                                                  const float* __restrict__ stats) {
    size_t total4 = (size_t)NN * STR / 4;
    size_t stride = (size_t)gridDim.x * 256;
    for (size_t i = (size_t)blockIdx.x * 256 + threadIdx.x; i < total4; i += stride) {
        int c = (int)((i * 4) % STR);
        float4 v = ((const float4*)x)[i];
        float4 m4 = *(const float4*)(stats + c);
        float4 q4 = *(const float4*)(stats + 512 + c);
        float4 o;
        o.x = bnleaky(v.x, m4.x, q4.x);
        o.y = bnleaky(v.y, m4.y, q4.y);
        o.z = bnleaky(v.z, m4.z, q4.z);
        o.w = bnleaky(v.w, m4.w, q4.w);
        ((float4*)x)[i] = o;
    }
}

// ---------------- pooling (input stride 64) ----------------
__global__ __launch_bounds__(256) void k_pool(const float* __restrict__ h,
                                              float* __restrict__ pooled) {
    int blk = blockIdx.x;
    int batch = blk >> 4, seg = blk & 15;
    int f = threadIdx.x & 63, g = threadIdx.x >> 6;
    size_t base = ((size_t)batch * 4096 + seg * 256 + g) * 64 + f;
    float acc = 0.f;
    for (int i = 0; i < 64; ++i) acc += h[base + (size_t)i * 256];
    atomicAdd(&pooled[batch * 64 + f], acc);
}

// ---------------- head ----------------
__global__ __launch_bounds__(256) void k_head(
    const float* __restrict__ gender, const float* __restrict__ age,
    const float* __restrict__ handed, const float* __restrict__ Wq,
    const float* __restrict__ bq, const float* __restrict__ Wk,
    const float* __restrict__ bk, const float* __restrict__ Wv,
    const float* __restrict__ bv, const float* __restrict__ Wfc,
    const float* __restrict__ bfc, const float* __restrict__ Wf1,
    const float* __restrict__ bf1, const float* __restrict__ Wf2,
    const float* __restrict__ bf2, const float* __restrict__ Wf3,
    const float* __restrict__ bf3, const float* __restrict__ pooled,
    float* __restrict__ dout) {
    __shared__ float plug[BS_][8];
    __shared__ float qs[BS_][32], ks[BS_][32], vs[BS_][32];
    __shared__ float gum[256];
    __shared__ float x32[BS_][32];
    __shared__ float px[BS_][4];
    __shared__ float embs[BS_][54];
    __shared__ float t1[BS_][32];
    __shared__ float t2[BS_][16];
    int t = threadIdx.x;

    if (t < 128) {
        int b = t >> 3, c = t & 7;
        float v;
        if (c < 2) v = gender[b * 2 + c];
        else if (c == 2) v = age[b];
        else v = handed[b * 5 + (c - 3)];
        plug[b][c] = v;
    }
    {
        u32 lane = (u32)(t & 127);
        u32 a = lane, b2 = lane + 128u;
        threefry_0_42(a, b2);
        u32 bits = (t < 128) ? a : b2;
        float u = __uint_as_float((bits >> 9) | 0x3f800000u) - 1.0f;
        const float mn = 1e-9f;
        u = u * (1.0f - mn) + mn;
        u = fmaxf(mn, u);
        gum[t] = -logf(-logf(u));
    }
    __syncthreads();
    for (int idx = t; idx < 512; idx += 256) {
        int b = idx >> 5, c = idx & 31;
        float aq = bq[c], ak = bk[c], av = bv[c];
#pragma unroll
        for (int i = 0; i < 8; ++i) {
            float p = plug[b][i];
            aq = fmaf(p, Wq[i * 32 + c], aq);
            ak = fmaf(p, Wk[i * 32 + c], ak);
            av = fmaf(p, Wv[i * 32 + c], av);
        }
        qs[b][c] = aq; ks[b][c] = ak; vs[b][c] = av;
    }
    __syncthreads();
    if (t < 64) {
        int b = t >> 2, h = t & 3;
        const float isq = 0.35355339059327373f;
        const float sq = 2.8284271247461903f;
        float sc[4];
#pragma unroll
        for (int j = 0; j < 4; ++j) {
            float d = 0.f;
#pragma unroll
            for (int dd = 0; dd < 8; ++dd) d = fmaf(qs[b][h * 8 + dd], ks[b][j * 8 + dd], d);
            sc[j] = d * isq + gum[b * 16 + h * 4 + j];
        }
        float m = fmaxf(fmaxf(sc[0], sc[1]), fmaxf(sc[2], sc[3]));
        float e0 = expf(sc[0] - m), e1 = expf(sc[1] - m), e2 = expf(sc[2] - m), e3 = expf(sc[3] - m);
        float sum = e0 + e1 + e2 + e3;
        float a0 = e0 / sum * sq, a1 = e1 / sum * sq, a2 = e2 / sum * sq, a3 = e3 / sum * sq;
#pragma unroll
        for (int dd = 0; dd < 8; ++dd) {
            float o = a0 * vs[b][0 * 8 + dd] + a1 * vs[b][1 * 8 + dd] +
                      a2 * vs[b][2 * 8 + dd] + a3 * vs[b][3 * 8 + dd];
            x32[b][h * 8 + dd] = o;
        }
    }
    __syncthreads();
    if (t < 64) {
        int b = t >> 2, n = t & 3;
        float a = bfc[n];
#pragma unroll
        for (int m = 0; m < 32; ++m) a = fmaf(x32[b][m], Wfc[m * 4 + n], a);
        px[b][n] = a;
    }
    __syncthreads();
    for (int idx = t; idx < BS_ * 54; idx += 256) {
        int b = idx / 54, c = idx % 54;
        float v = (c < 50) ? pooled[b * 64 + c] : px[b][c - 50];
        embs[b][c] = v;
        dout[16 + idx] = v;
    }
    __syncthreads();
    for (int idx = t; idx < 512; idx += 256) {
        int b = idx >> 5, c = idx & 31;
        float a = bf1[c];
#pragma unroll
        for (int k = 0; k < 54; ++k) a = fmaf(embs[b][k], Wf1[k * 32 + c], a);
        t1[b][c] = a;
    }
    __syncthreads();
    {
        int b = t >> 4, c = t & 15;
        float a = bf2[c];
#pragma unroll
        for (int k = 0; k < 32; ++k) a = fmaf(t1[b][k], Wf2[k * 16 + c], a);
        t2[b][c] = a;
    }
    __syncthreads();
    if (t < 16) {
        float a = bf3[0];
#pragma unroll
        for (int k = 0; k < 16; ++k) a = fmaf(t2[t][k], Wf3[k], a);
        dout[t] = a;
    }
}

// ---------------- launcher ----------------
extern "C" void kernel_launch(void* const* d_in, const int* in_sizes, int n_in,
                              void* d_out, int out_size, void* d_ws, size_t ws_size,
                              hipStream_t stream) {
    const float* x      = (const float*)d_in[0];
    const int*   ei     = (const int*)d_in[1];
    const float* gender = (const float*)d_in[2];
    const float* age    = (const float*)d_in[3];
    const float* handed = (const float*)d_in[4];
    const float* W1  = (const float*)d_in[5];
    const float* b1  = (const float*)d_in[6];
    const float* Wl2 = (const float*)d_in[7];
    const float* Wr2 = (const float*)d_in[8];
    const float* b2  = (const float*)d_in[9];
    const float* Wl3 = (const float*)d_in[10];
    const float* Wr3 = (const float*)d_in[11];
    const float* b3  = (const float*)d_in[12];
    const float* Wl4 = (const float*)d_in[13];
    const float* Wr4 = (const float*)d_in[14];
    const float* b4  = (const float*)d_in[15];
    const float* Wq  = (const float*)d_in[16];
    const float* bq  = (const float*)d_in[17];
    const float* Wk  = (const float*)d_in[18];
    const float* bk  = (const float*)d_in[19];
    const float* Wv  = (const float*)d_in[20];
    const float* bv  = (const float*)d_in[21];
    const float* Wfc = (const float*)d_in[22];
    const float* bfc = (const float*)d_in[23];
    const float* Wf1 = (const float*)d_in[24];
    const float* bf1 = (const float*)d_in[25];
    const float* Wf2 = (const float*)d_in[26];
    const float* bf2 = (const float*)d_in[27];
    const float* Wf3 = (const float*)d_in[28];
    const float* bf3 = (const float*)d_in[29];

    const int* srcp = ei;
    const int* dstp = ei + EE;

    char* wsb = (char*)d_ws;
    size_t off = 0;
    auto alloc = [&](size_t bytes) -> char* {
        char* p = wsb + off;
        off += (bytes + 255) & ~(size_t)255;
        return p;
    };
    float* P = (float*)alloc((size_t)NN * 320 * 4);
    float* Q = (float*)alloc((size_t)NN * 320 * 4);
    float* R = (float*)alloc((size_t)NN * 192 * 4);
    float* T = (float*)alloc((size_t)NN * 192 * 4);
    int* indeg  = (int*)alloc((size_t)NN * 4);
    int* rowptr = (int*)alloc((size_t)(NN + 1) * 4);
    int* cursor = (int*)alloc((size_t)(NN + 1) * 4);
    int* csr    = (int*)alloc((size_t)EE * 4);
    float* dinv = (float*)alloc((size_t)NN * 4);
    float* stats  = (float*)alloc(4096 * 4);  // 4 regions x 1024
    float* pooled = (float*)alloc(16 * 64 * 4);
    // stacked weight splits: [NPW][KP] bf16 hi/lo
    u16* W1h = (u16*)alloc((size_t)384 * 640 * 2);
    u16* W1l = (u16*)alloc((size_t)384 * 640 * 2);
    u16* W2h = (u16*)alloc((size_t)384 * 320 * 2);
    u16* W2l = (u16*)alloc((size_t)384 * 320 * 2);
    u16* W3h = (u16*)alloc((size_t)256 * 192 * 2);
    u16* W3l = (u16*)alloc((size_t)256 * 192 * 2);
    u16* W4h = (u16*)alloc((size_t)128 * 128 * 2);
    u16* W4l = (u16*)alloc((size_t)128 * 128 * 2);
    float* dout = (float*)d_out;

    // graph preprocessing
    hipMemsetAsync(indeg, 0, (size_t)NN * 4, stream);
    hipMemsetAsync(stats, 0, 4096 * 4, stream);
    k_indeg<<<EE / 256, 256, 0, stream>>>(dstp, indeg);
    k_scan<<<1, 256, 0, stream>>>(indeg, rowptr, cursor);
    k_fill<<<EE / 256, 256, 0, stream>>>(srcp, dstp, cursor, csr);
    k_dinv<<<NN / 256, 256, 0, stream>>>(indeg, dinv);

    // weight splits (stacked [Wr | Wl])
    k_wsplit2<<<(384 * 640 + 255) / 256, 256, 0, stream>>>(W1, nullptr, 640, 320, 640, 320, 384, W1h, W1l);
    k_wsplit2<<<(384 * 320 + 255) / 256, 256, 0, stream>>>(Wr2, Wl2, 320, 180, 320, 192, 384, W2h, W2l);
    k_wsplit2<<<(256 * 192 + 255) / 256, 256, 0, stream>>>(Wr3, Wl3, 180, 90, 192, 128, 256, W3h, W3l);
    k_wsplit2<<<(128 * 128 + 255) / 256, 256, 0, stream>>>(Wr4, Wl4, 90, 50, 128, 64, 128, W4h, W4l);

    // layer 1: GCN (640 -> 320).  P = x @ W1 ; Q = gcn_agg(P) + b1 (raw, pre-BN)
    k_gemm_mfma<false, false><<<dim3(1024, 3), 256, 0, stream>>>(
        x, W1h, W1l, 640, 640, nullptr, nullptr, P, nullptr, 320, 320);
    k_gcn_agg320<<<NN / 4, 256, 0, stream>>>(P, rowptr, csr, dinv, b1, Q);
    k_bn_stats<320, 320><<<1024, 256, 0, stream>>>(Q, stats);

    // layer 2: SAGE (320 -> 180, stride 192).  [R | T] = bn(Q) @ [Wr2 | Wl2]; R += mean(T)
    k_gemm_mfma<true, true><<<dim3(1024, 3), 256, 0, stream>>>(
        Q, W2h, W2l, 320, 320, stats, b2, R, T, 180, 192);
    k_agg_add<48, 0><<<NN / 4, 256, 0, stream>>>(T, rowptr, csr, indeg, R);
    k_bn_stats<180, 192><<<1024, 256, 0, stream>>>(R, stats + 1024);

    // layer 3: SAGE (180 -> 90, stride 128).  [P | T] = bn(R) @ [Wr3 | Wl3]; P += mean(T)
    k_gemm_mfma<true, true><<<dim3(1024, 2), 256, 0, stream>>>(
        R, W3h, W3l, 192, 192, stats + 1024, b3, P, T, 90, 128);
    k_agg_add<32, 1><<<NN / 8, 256, 0, stream>>>(T, rowptr, csr, indeg, P);
    k_bn_stats<90, 128><<<1024, 256, 0, stream>>>(P, stats + 2048);

    // layer 4: SAGE (90 -> 50, stride 64).  [Q | T] = bn(P) @ [Wr4 | Wl4]; Q += mean(T)
    k_gemm_mfma<true, true><<<dim3(1024, 1), 256, 0, stream>>>(
        P, W4h, W4l, 128, 128, stats + 2048, b4, Q, T, 50, 64);
    k_agg_add<16, 2><<<NN / 16, 256, 0, stream>>>(T, rowptr, csr, indeg, Q);
    k_bn_stats<50, 64><<<1024, 256, 0, stream>>>(Q, stats + 3072);
    k_bn_apply<64><<<2048, 256, 0, stream>>>(Q, stats + 3072);

    // pooling + head
    hipMemsetAsync(pooled, 0, 16 * 64 * 4, stream);
    k_pool<<<256, 256, 0, stream>>>(Q, pooled);
    k_head<<<1, 256, 0, stream>>>(gender, age, handed, Wq, bq, Wk, bk, Wv, bv,
                                  Wfc, bfc, Wf1, bf1, Wf2, bf2, Wf3, bf3, pooled, dout);
}

// Round 10
// 997.208 us; speedup vs baseline: 1.3963x; 1.0533x over previous
//
#include <hip/hip_runtime.h>
#include <cstdint>

#define NN 65536
#define EE 524288
#define BS_ 16

typedef unsigned short u16;
typedef unsigned int u32;
typedef __attribute__((ext_vector_type(8))) short short8v;
typedef __attribute__((ext_vector_type(4))) float f32x4;

// ---------------- bf16 helpers ----------------
__device__ __forceinline__ u16 f2bf(float f) {
    u32 u = __float_as_uint(f);
    u32 r = (u + 0x7fffu + ((u >> 16) & 1u)) >> 16;
    return (u16)r;
}
__device__ __forceinline__ float bff(u16 h) {
    return __uint_as_float(((u32)h) << 16);
}

// async global->LDS, 16B per lane (dest = wave-uniform base + lane*16)
__device__ __forceinline__ void gload_lds16(const void* g, void* l) {
    __builtin_amdgcn_global_load_lds(
        (const __attribute__((address_space(1))) void*)g,
        (__attribute__((address_space(3))) void*)l, 16, 0, 0);
}

// leaky_relu + batchnorm affine from raw sums
__device__ __forceinline__ float bnleaky(float v, float s, float q) {
    const float invN = 1.0f / 65536.0f;
    float mu = s * invN;
    float var = q * invN - mu * mu;
    float u = v >= 0.f ? v : 0.01f * v;
    return (u - mu) * rsqrtf(var + 1e-5f);
}

// ---------------- threefry2x32 (JAX-compatible, key = (0,42)) ----------------
__device__ __forceinline__ u32 rotl32(u32 x, int d) {
    return (x << d) | (x >> (32 - d));
}
__device__ __forceinline__ void threefry_0_42(u32& x0, u32& x1) {
    const u32 ks0 = 0u, ks1 = 42u, ks2 = 0u ^ 42u ^ 0x1BD11BDAu;
    x0 += ks0; x1 += ks1;
#define RND(r) { x0 += x1; x1 = rotl32(x1, r); x1 ^= x0; }
    RND(13) RND(15) RND(26) RND(6)  x0 += ks1; x1 += ks2 + 1u;
    RND(17) RND(29) RND(16) RND(24) x0 += ks2; x1 += ks0 + 2u;
    RND(13) RND(15) RND(26) RND(6)  x0 += ks0; x1 += ks1 + 3u;
    RND(17) RND(29) RND(16) RND(24) x0 += ks1; x1 += ks2 + 4u;
    RND(13) RND(15) RND(26) RND(6)  x0 += ks2; x1 += ks0 + 5u;
#undef RND
}

// ---------------- graph preprocessing ----------------
__global__ void k_indeg(const int* __restrict__ dst, int* __restrict__ indeg) {
    int e = blockIdx.x * 256 + threadIdx.x;
    if (e < EE) atomicAdd(&indeg[dst[e]], 1);
}

// hierarchical scan: block sums -> 256-prefix -> scatter
__global__ void k_scan1(const int* __restrict__ indeg, int* __restrict__ bsum) {
    __shared__ int red[256];
    int t = threadIdx.x;
    red[t] = indeg[blockIdx.x * 256 + t];
    __syncthreads();
    for (int o = 128; o > 0; o >>= 1) {
        if (t < o) red[t] += red[t + o];
        __syncthreads();
    }
    if (t == 0) bsum[blockIdx.x] = red[0];
}

__global__ void k_scan2(const int* __restrict__ bsum, int* __restrict__ boff) {
    __shared__ int ps[256];
    int t = threadIdx.x;
    int orig = bsum[t];
    ps[t] = orig;
    __syncthreads();
    for (int o = 1; o < 256; o <<= 1) {
        int v = (t >= o) ? ps[t - o] : 0;
        __syncthreads();
        ps[t] += v;
        __syncthreads();
    }
    boff[t] = ps[t] - orig;
}

__global__ void k_scan3(const int* __restrict__ indeg, const int* __restrict__ boff,
                        int* __restrict__ rowptr, int* __restrict__ cursor) {
    __shared__ int ps[256];
    int b = blockIdx.x, t = threadIdx.x;
    int v = indeg[b * 256 + t];
    ps[t] = v;
    __syncthreads();
    for (int o = 1; o < 256; o <<= 1) {
        int u = (t >= o) ? ps[t - o] : 0;
        __syncthreads();
        ps[t] += u;
        __syncthreads();
    }
    int ex = boff[b] + ps[t] - v;
    rowptr[b * 256 + t] = ex;
    cursor[b * 256 + t] = ex;
    if (b == 255 && t == 255) rowptr[NN] = ex + v;
}

__global__ void k_fill(const int* __restrict__ src, const int* __restrict__ dst,
                       int* __restrict__ cursor, int* __restrict__ csr) {
    int e = blockIdx.x * 256 + threadIdx.x;
    if (e < EE) {
        int d = dst[e];
        int p = atomicAdd(&cursor[d], 1);
        csr[p] = src[e];
    }
}

__global__ void k_dinv(const int* __restrict__ indeg, float* __restrict__ dinv) {
    int i = blockIdx.x * 256 + threadIdx.x;
    if (i < NN) dinv[i] = rsqrtf((float)indeg[i] + 1.0f);
}

// ---------------- stacked weight transpose + hi/lo split, tiled+swizzled ------
// Output: tiles of 128 rows x 64 k, contiguous 8192 u16 each, tile index
// (nb, kb) -> (nb*(KP/64)+kb)*8192. Within tile, element (nn, kk) at u16
// offset nn*64 + (((kk>>3) ^ (nn&7))<<3) + (kk&7)  [XOR swizzle baked in].
__global__ void k_wsplit2(const float* __restrict__ Wr, const float* __restrict__ Wlsrc,
                          int K, int N, int KP, int CS, int NPW,
                          u16* __restrict__ Wh, u16* __restrict__ Wl) {
    int idx = blockIdx.x * 256 + threadIdx.x;
    if (idx >= NPW * KP) return;
    int n = idx / KP, k = idx % KP;
    float v = 0.f;
    if (n < CS) {
        if (n < N && k < K) v = Wr[(size_t)k * N + n];
    } else {
        int n2 = n - CS;
        if (Wlsrc != nullptr && n2 < N && k < K) v = Wlsrc[(size_t)k * N + n2];
    }
    u16 h = f2bf(v);
    u16 l = f2bf(v - bff(h));
    int nb = n >> 7, nn = n & 127, kb = k >> 6, kk = k & 63;
    size_t o = ((size_t)nb * (KP >> 6) + kb) * 8192
             + nn * 64 + (((kk >> 3) ^ (nn & 7)) << 3) + (kk & 7);
    Wh[o] = h;
    Wl[o] = l;
}

// ---------------- bf16 MFMA GEMM: A-hi x (W-hi + W-lo) ----------------
// Block 64 rows x 128 cols, 4 waves (2x2); grid dim3(M/64, NT) M-fastest.
// W staged via global_load_lds (async, 1KB/instr) from tiled+swizzled layout;
// A staged through VGPRs (fp32 -> BN+leaky -> bf16) into padded LDS.
template <bool HASB, bool HASBN>
__global__ __launch_bounds__(256, 3) void k_gemm_mfma(
    const float* __restrict__ A, const u16* __restrict__ Wgh, const u16* __restrict__ Wgl,
    int KP, int lda, const float* __restrict__ bns,
    const float* __restrict__ bias, float* __restrict__ O1, float* __restrict__ O2,
    int N, int CS) {
    __shared__ u16 Ah[64][72];
    __shared__ u16 WhL[8192];
    __shared__ u16 WlL[8192];

    const int t = threadIdx.x;
    const int bm = blockIdx.x * 64;
    const int lane = t & 63;
    const int wid = t >> 6;
    const int wr = wid >> 1, wc = wid & 1;

    f32x4 acc[2][4];
#pragma unroll
    for (int m = 0; m < 2; ++m)
#pragma unroll
        for (int n = 0; n < 4; ++n) acc[m][n] = (f32x4){0.f, 0.f, 0.f, 0.f};

    const int sr = t >> 4;
    const int sc4 = (t & 15) * 4;
    const int nkb = KP >> 6;

    for (int k0 = 0; k0 < KP; k0 += 64) {
        // W: async global->LDS (8 x 1KB per wave), swizzle baked into source
        {
            const size_t wtile = ((size_t)blockIdx.y * nkb + (k0 >> 6)) * 8192;
            const int cb = wid * 2048;
#pragma unroll
            for (int c = 0; c < 4; ++c) {
                int o = cb + c * 512;
                gload_lds16(Wgh + wtile + o + lane * 8, &WhL[o]);
                gload_lds16(Wgl + wtile + o + lane * 8, &WlL[o]);
            }
        }
        // A: fp32 load -> BN+leaky -> bf16 -> LDS
        float4 s4, q4;
        if (HASBN) {
            s4 = *(const float4*)(bns + k0 + sc4);
            q4 = *(const float4*)(bns + 512 + k0 + sc4);
        }
#pragma unroll
        for (int p = 0; p < 4; ++p) {
            int rr = sr + 16 * p;
            float4 v = *(const float4*)(A + (size_t)(bm + rr) * lda + k0 + sc4);
            if (HASBN) {
                v.x = bnleaky(v.x, s4.x, q4.x);
                v.y = bnleaky(v.y, s4.y, q4.y);
                v.z = bnleaky(v.z, s4.z, q4.z);
                v.w = bnleaky(v.w, s4.w, q4.w);
            }
            uint2 hh;
            hh.x = (u32)f2bf(v.x) | ((u32)f2bf(v.y) << 16);
            hh.y = (u32)f2bf(v.z) | ((u32)f2bf(v.w) << 16);
            *(uint2*)&Ah[rr][sc4] = hh;
        }
        __syncthreads();
        const int fr = lane & 15;
        const int kg8 = lane >> 4;      // k-group: elems kg8*8 .. kg8*8+7
        const int kg = kg8 * 8;
#pragma unroll
        for (int kk = 0; kk < 64; kk += 32) {
            short8v a_h[2], w_h[4], w_l[4];
#pragma unroll
            for (int m = 0; m < 2; ++m)
                a_h[m] = *(const short8v*)&Ah[wr * 32 + m * 16 + fr][kk + kg];
#pragma unroll
            for (int n = 0; n < 4; ++n) {
                int r = wc * 64 + n * 16 + fr;
                int slot = (kk >> 3) + kg8;
                int o = r * 64 + ((slot ^ (r & 7)) << 3);
                w_h[n] = *(const short8v*)&WhL[o];
                w_l[n] = *(const short8v*)&WlL[o];
            }
#pragma unroll
            for (int m = 0; m < 2; ++m)
#pragma unroll
                for (int n = 0; n < 4; ++n) {
                    acc[m][n] = __builtin_amdgcn_mfma_f32_16x16x32_bf16(a_h[m], w_h[n], acc[m][n], 0, 0, 0);
                    acc[m][n] = __builtin_amdgcn_mfma_f32_16x16x32_bf16(a_h[m], w_l[n], acc[m][n], 0, 0, 0);
                }
        }
        __syncthreads();
    }
    const int bn = blockIdx.y * 128;
    const int fr = lane & 15, fq = lane >> 4;
#pragma unroll
    for (int m = 0; m < 2; ++m) {
        int row = bm + wr * 32 + m * 16 + fq * 4;
#pragma unroll
        for (int n = 0; n < 4; ++n) {
            int col = bn + wc * 64 + n * 16 + fr;
            if (col < CS) {
                float b = (HASB && col < N) ? bias[col] : 0.f;
#pragma unroll
                for (int e = 0; e < 4; ++e)
                    O1[(size_t)(row + e) * CS + col] = acc[m][n][e] + b;
            } else if (O2 != nullptr) {
                int c2 = col - CS;
#pragma unroll
                for (int e = 0; e < 4; ++e)
                    O2[(size_t)(row + e) * CS + c2] = acc[m][n][e];
            }
        }
    }
}

// ---------------- GCN aggregation, D=320 (float4, edge unroll-4) ----------------
__global__ __launch_bounds__(256) void k_gcn_agg320(const float* __restrict__ h,
                                                    const int* __restrict__ rowptr,
                                                    const int* __restrict__ csr,
                                                    const float* __restrict__ dinv,
                                                    const float* __restrict__ bias,
                                                    float* __restrict__ out) {
    int lane = threadIdx.x & 63;
    int n = blockIdx.x * 4 + (threadIdx.x >> 6);
    bool has1 = lane < 16;
    float di = dinv[n];
    float s2 = di * di;
    const float4* hn = (const float4*)(h + (size_t)n * 320);
    float4 v0 = hn[lane];
    float4 a0 = make_float4(v0.x * s2, v0.y * s2, v0.z * s2, v0.w * s2);
    float4 a1 = make_float4(0.f, 0.f, 0.f, 0.f);
    if (has1) {
        float4 v1 = hn[64 + lane];
        a1 = make_float4(v1.x * s2, v1.y * s2, v1.z * s2, v1.w * s2);
    }
    int e = rowptr[n], e1 = rowptr[n + 1];
    for (; e + 4 <= e1; e += 4) {
        int s0 = csr[e], s1 = csr[e + 1], s2i = csr[e + 2], s3 = csr[e + 3];
        float w0 = dinv[s0] * di, w1 = dinv[s1] * di, w2 = dinv[s2i] * di, w3 = dinv[s3] * di;
        const float4* p0 = (const float4*)(h + (size_t)s0 * 320);
        const float4* p1 = (const float4*)(h + (size_t)s1 * 320);
        const float4* p2 = (const float4*)(h + (size_t)s2i * 320);
        const float4* p3 = (const float4*)(h + (size_t)s3 * 320);
        float4 u0 = p0[lane], u1 = p1[lane], u2 = p2[lane], u3 = p3[lane];
        a0.x += u0.x * w0 + u1.x * w1 + u2.x * w2 + u3.x * w3;
        a0.y += u0.y * w0 + u1.y * w1 + u2.y * w2 + u3.y * w3;
        a0.z += u0.z * w0 + u1.z * w1 + u2.z * w2 + u3.z * w3;
        a0.w += u0.w * w0 + u1.w * w1 + u2.w * w2 + u3.w * w3;
        if (has1) {
            float4 x0 = p0[64 + lane], x1 = p1[64 + lane], x2 = p2[64 + lane], x3 = p3[64 + lane];
            a1.x += x0.x * w0 + x1.x * w1 + x2.x * w2 + x3.x * w3;
            a1.y += x0.y * w0 + x1.y * w1 + x2.y * w2 + x3.y * w3;
            a1.z += x0.z * w0 + x1.z * w1 + x2.z * w2 + x3.z * w3;
            a1.w += x0.w * w0 + x1.w * w1 + x2.w * w2 + x3.w * w3;
        }
    }
    for (; e < e1; ++e) {
        int s = csr[e];
        float w = dinv[s] * di;
        const float4* hs = (const float4*)(h + (size_t)s * 320);
        float4 u0 = hs[lane];
        a0.x = fmaf(u0.x, w, a0.x); a0.y = fmaf(u0.y, w, a0.y);
        a0.z = fmaf(u0.z, w, a0.z); a0.w = fmaf(u0.w, w, a0.w);
        if (has1) {
            float4 u1 = hs[64 + lane];
            a1.x = fmaf(u1.x, w, a1.x); a1.y = fmaf(u1.y, w, a1.y);
            a1.z = fmaf(u1.z, w, a1.z); a1.w = fmaf(u1.w, w, a1.w);
        }
    }
    const float4* b4 = (const float4*)bias;
    float4* on = (float4*)(out + (size_t)n * 320);
    float4 bb = b4[lane];
    on[lane] = make_float4(a0.x + bb.x, a0.y + bb.y, a0.z + bb.z, a0.w + bb.w);
    if (has1) {
        float4 bb1 = b4[64 + lane];
        on[64 + lane] = make_float4(a1.x + bb1.x, a1.y + bb1.y, a1.z + bb1.z, a1.w + bb1.w);
    }
}

// ---------------- C[n] += mean-gather(T[s]); stride = 4*CH floats ----------------
template <int CH, int LOG_NPW>
__global__ __launch_bounds__(256) void k_agg_add(const float* __restrict__ T,
                                                 const int* __restrict__ rowptr,
                                                 const int* __restrict__ csr,
                                                 const int* __restrict__ indeg,
                                                 float* __restrict__ C) {
    constexpr int NPW = 1 << LOG_NPW;
    constexpr int LPN = 64 >> LOG_NPW;
    constexpr int SC = CH * 4;
    int lane = threadIdx.x & 63;
    int sub = lane / LPN;
    int ch = lane & (LPN - 1);
    int n = (blockIdx.x * 4 + (threadIdx.x >> 6)) * NPW + sub;
    bool act = ch < CH;
    float4 acc = make_float4(0.f, 0.f, 0.f, 0.f);
    int e = rowptr[n], e1 = rowptr[n + 1];
    for (; e + 4 <= e1; e += 4) {
        int s0 = csr[e], s1 = csr[e + 1], s2 = csr[e + 2], s3 = csr[e + 3];
        if (act) {
            float4 u0 = *(const float4*)(T + (size_t)s0 * SC + ch * 4);
            float4 u1 = *(const float4*)(T + (size_t)s1 * SC + ch * 4);
            float4 u2 = *(const float4*)(T + (size_t)s2 * SC + ch * 4);
            float4 u3 = *(const float4*)(T + (size_t)s3 * SC + ch * 4);
            acc.x += (u0.x + u1.x) + (u2.x + u3.x);
            acc.y += (u0.y + u1.y) + (u2.y + u3.y);
            acc.z += (u0.z + u1.z) + (u2.z + u3.z);
            acc.w += (u0.w + u1.w) + (u2.w + u3.w);
        }
    }
    for (; e < e1; ++e) {
        int s = csr[e];
        if (act) {
            float4 u = *(const float4*)(T + (size_t)s * SC + ch * 4);
            acc.x += u.x; acc.y += u.y; acc.z += u.z; acc.w += u.w;
        }
    }
    int cnt = indeg[n];
    float inv = 1.0f / (float)(cnt > 1 ? cnt : 1);
    if (act) {
        float4* cp = (float4*)(C + (size_t)n * SC + ch * 4);
        float4 c = *cp;
        c.x = fmaf(acc.x, inv, c.x);
        c.y = fmaf(acc.y, inv, c.y);
        c.z = fmaf(acc.z, inv, c.z);
        c.w = fmaf(acc.w, inv, c.w);
        *cp = c;
    }
}

// ---------------- batchnorm stats (leaky fused); 1024 blocks x 64 rows ----------------
template <int D, int STR>
__global__ __launch_bounds__(256) void k_bn_stats(const float* __restrict__ x,
                                                  float* __restrict__ stats) {
    constexpr int NC = (D + 255) / 256;
    int t = threadIdx.x;
    int r0 = blockIdx.x * 64;
    float s[NC], q[NC];
#pragma unroll
    for (int i = 0; i < NC; ++i) { s[i] = 0.f; q[i] = 0.f; }
#pragma unroll 4
    for (int r = r0; r < r0 + 64; ++r) {
        const float* row = x + (size_t)r * STR;
#pragma unroll
        for (int i = 0; i < NC; ++i) {
            int c = t + 256 * i;
            if (c < D) {
                float v = row[c];
                v = v >= 0.f ? v : 0.01f * v;
                s[i] += v;
                q[i] += v * v;
            }
        }
    }
#pragma unroll
    for (int i = 0; i < NC; ++i) {
        int c = t + 256 * i;
        if (c < D) {
            atomicAdd(&stats[c], s[i]);
            atomicAdd(&stats[512 + c], q[i]);
        }
    }
}

template <int STR>
__global__ __launch_bounds__(256) void k_bn_apply(float* __restrict__ x,
                                                  const float* __restrict__ stats) {
    size_t total4 = (size_t)NN * STR / 4;
    size_t stride = (size_t)gridDim.x * 256;
    for (size_t i = (size_t)blockIdx.x * 256 + threadIdx.x; i < total4; i += stride) {
        int c = (int)((i * 4) % STR);
        float4 v = ((const float4*)x)[i];
        float4 m4 = *(const float4*)(stats + c);
        float4 q4 = *(const float4*)(stats + 512 + c);
        float4 o;
        o.x = bnleaky(v.x, m4.x, q4.x);
        o.y = bnleaky(v.y, m4.y, q4.y);
        o.z = bnleaky(v.z, m4.z, q4.z);
        o.w = bnleaky(v.w, m4.w, q4.w);
        ((float4*)x)[i] = o;
    }
}

// ---------------- pooling (input stride 64) ----------------
__global__ __launch_bounds__(256) void k_pool(const float* __restrict__ h,
                                              float* __restrict__ pooled) {
    int blk = blockIdx.x;
    int batch = blk >> 4, seg = blk & 15;
    int f = threadIdx.x & 63, g = threadIdx.x >> 6;
    size_t base = ((size_t)batch * 4096 + seg * 256 + g) * 64 + f;
    float acc = 0.f;
    for (int i = 0; i < 64; ++i) acc += h[base + (size_t)i * 256];
    atomicAdd(&pooled[batch * 64 + f], acc);
}

// ---------------- head ----------------
__global__ __launch_bounds__(256) void k_head(
    const float* __restrict__ gender, const float* __restrict__ age,
    const float* __restrict__ handed, const float* __restrict__ Wq,
    const float* __restrict__ bq, const float* __restrict__ Wk,
    const float* __restrict__ bk, const float* __restrict__ Wv,
    const float* __restrict__ bv, const float* __restrict__ Wfc,
    const float* __restrict__ bfc, const float* __restrict__ Wf1,
    const float* __restrict__ bf1, const float* __restrict__ Wf2,
    const float* __restrict__ bf2, const float* __restrict__ Wf3,
    const float* __restrict__ bf3, const float* __restrict__ pooled,
    float* __restrict__ dout) {
    __shared__ float plug[BS_][8];
    __shared__ float qs[BS_][32], ks[BS_][32], vs[BS_][32];
    __shared__ float gum[256];
    __shared__ float x32[BS_][32];
    __shared__ float px[BS_][4];
    __shared__ float embs[BS_][54];
    __shared__ float t1[BS_][32];
    __shared__ float t2[BS_][16];
    int t = threadIdx.x;

    if (t < 128) {
        int b = t >> 3, c = t & 7;
        float v;
        if (c < 2) v = gender[b * 2 + c];
        else if (c == 2) v = age[b];
        else v = handed[b * 5 + (c - 3)];
        plug[b][c] = v;
    }
    {
        u32 lane = (u32)(t & 127);
        u32 a = lane, b2 = lane + 128u;
        threefry_0_42(a, b2);
        u32 bits = (t < 128) ? a : b2;
        float u = __uint_as_float((bits >> 9) | 0x3f800000u) - 1.0f;
        const float mn = 1e-9f;
        u = u * (1.0f - mn) + mn;
        u = fmaxf(mn, u);
        gum[t] = -logf(-logf(u));
    }
    __syncthreads();
    for (int idx = t; idx < 512; idx += 256) {
        int b = idx >> 5, c = idx & 31;
        float aq = bq[c], ak = bk[c], av = bv[c];
#pragma unroll
        for (int i = 0; i < 8; ++i) {
            float p = plug[b][i];
            aq = fmaf(p, Wq[i * 32 + c], aq);
            ak = fmaf(p, Wk[i * 32 + c], ak);
            av = fmaf(p, Wv[i * 32 + c], av);
        }
        qs[b][c] = aq; ks[b][c] = ak; vs[b][c] = av;
    }
    __syncthreads();
    if (t < 64) {
        int b = t >> 2, h = t & 3;
        const float isq = 0.35355339059327373f;
        const float sq = 2.8284271247461903f;
        float sc[4];
#pragma unroll
        for (int j = 0; j < 4; ++j) {
            float d = 0.f;
#pragma unroll
            for (int dd = 0; dd < 8; ++dd) d = fmaf(qs[b][h * 8 + dd], ks[b][j * 8 + dd], d);
            sc[j] = d * isq + gum[b * 16 + h * 4 + j];
        }
        float m = fmaxf(fmaxf(sc[0], sc[1]), fmaxf(sc[2], sc[3]));
        float e0 = expf(sc[0] - m), e1 = expf(sc[1] - m), e2 = expf(sc[2] - m), e3 = expf(sc[3] - m);
        float sum = e0 + e1 + e2 + e3;
        float a0 = e0 / sum * sq, a1 = e1 / sum * sq, a2 = e2 / sum * sq, a3 = e3 / sum * sq;
#pragma unroll
        for (int dd = 0; dd < 8; ++dd) {
            float o = a0 * vs[b][0 * 8 + dd] + a1 * vs[b][1 * 8 + dd] +
                      a2 * vs[b][2 * 8 + dd] + a3 * vs[b][3 * 8 + dd];
            x32[b][h * 8 + dd] = o;
        }
    }
    __syncthreads();
    if (t < 64) {
        int b = t >> 2, n = t & 3;
        float a = bfc[n];
#pragma unroll
        for (int m = 0; m < 32; ++m) a = fmaf(x32[b][m], Wfc[m * 4 + n], a);
        px[b][n] = a;
    }
    __syncthreads();
    for (int idx = t; idx < BS_ * 54; idx += 256) {
        int b = idx / 54, c = idx % 54;
        float v = (c < 50) ? pooled[b * 64 + c] : px[b][c - 50];
        embs[b][c] = v;
        dout[16 + idx] = v;
    }
    __syncthreads();
    for (int idx = t; idx < 512; idx += 256) {
        int b = idx >> 5, c = idx & 31;
        float a = bf1[c];
#pragma unroll
        for (int k = 0; k < 54; ++k) a = fmaf(embs[b][k], Wf1[k * 32 + c], a);
        t1[b][c] = a;
    }
    __syncthreads();
    {
        int b = t >> 4, c = t & 15;
        float a = bf2[c];
#pragma unroll
        for (int k = 0; k < 32; ++k) a = fmaf(t1[b][k], Wf2[k * 16 + c], a);
        t2[b][c] = a;
    }
    __syncthreads();
    if (t < 16) {
        float a = bf3[0];
#pragma unroll
        for (int k = 0; k < 16; ++k) a = fmaf(t2[t][k], Wf3[k], a);
        dout[t] = a;
    }
}

// ---------------- launcher ----------------
extern "C" void kernel_launch(void* const* d_in, const int* in_sizes, int n_in,
                              void* d_out, int out_size, void* d_ws, size_t ws_size,
                              hipStream_t stream) {
    const float* x      = (const float*)d_in[0];
    const int*   ei     = (const int*)d_in[1];
    const float* gender = (const float*)d_in[2];
    const float* age    = (const float*)d_in[3];
    const float* handed = (const float*)d_in[4];
    const float* W1  = (const float*)d_in[5];
    const float* b1  = (const float*)d_in[6];
    const float* Wl2 = (const float*)d_in[7];
    const float* Wr2 = (const float*)d_in[8];
    const float* b2  = (const float*)d_in[9];
    const float* Wl3 = (const float*)d_in[10];
    const float* Wr3 = (const float*)d_in[11];
    const float* b3  = (const float*)d_in[12];
    const float* Wl4 = (const float*)d_in[13];
    const float* Wr4 = (const float*)d_in[14];
    const float* b4  = (const float*)d_in[15];
    const float* Wq  = (const float*)d_in[16];
    const float* bq  = (const float*)d_in[17];
    const float* Wk  = (const float*)d_in[18];
    const float* bk  = (const float*)d_in[19];
    const float* Wv  = (const float*)d_in[20];
    const float* bv  = (const float*)d_in[21];
    const float* Wfc = (const float*)d_in[22];
    const float* bfc = (const float*)d_in[23];
    const float* Wf1 = (const float*)d_in[24];
    const float* bf1 = (const float*)d_in[25];
    const float* Wf2 = (const float*)d_in[26];
    const float* bf2 = (const float*)d_in[27];
    const float* Wf3 = (const float*)d_in[28];
    const float* bf3 = (const float*)d_in[29];

    const int* srcp = ei;
    const int* dstp = ei + EE;

    char* wsb = (char*)d_ws;
    size_t off = 0;
    auto alloc = [&](size_t bytes) -> char* {
        char* p = wsb + off;
        off += (bytes + 255) & ~(size_t)255;
        return p;
    };
    float* P = (float*)alloc((size_t)NN * 320 * 4);
    float* Q = (float*)alloc((size_t)NN * 320 * 4);
    float* R = (float*)alloc((size_t)NN * 192 * 4);
    float* T = (float*)alloc((size_t)NN * 192 * 4);
    int* indeg  = (int*)alloc((size_t)NN * 4);
    int* rowptr = (int*)alloc((size_t)(NN + 1) * 4);
    int* cursor = (int*)alloc((size_t)(NN + 1) * 4);
    int* csr    = (int*)alloc((size_t)EE * 4);
    float* dinv = (float*)alloc((size_t)NN * 4);
    int* bsum   = (int*)alloc(256 * 4);
    int* boff   = (int*)alloc(257 * 4);
    float* stats  = (float*)alloc(4096 * 4);  // 4 regions x 1024
    float* pooled = (float*)alloc(16 * 64 * 4);
    // tiled+swizzled weight splits
    u16* W1h = (u16*)alloc((size_t)384 * 640 * 2);
    u16* W1l = (u16*)alloc((size_t)384 * 640 * 2);
    u16* W2h = (u16*)alloc((size_t)384 * 320 * 2);
    u16* W2l = (u16*)alloc((size_t)384 * 320 * 2);
    u16* W3h = (u16*)alloc((size_t)256 * 192 * 2);
    u16* W3l = (u16*)alloc((size_t)256 * 192 * 2);
    u16* W4h = (u16*)alloc((size_t)128 * 128 * 2);
    u16* W4l = (u16*)alloc((size_t)128 * 128 * 2);
    float* dout = (float*)d_out;

    // graph preprocessing
    hipMemsetAsync(indeg, 0, (size_t)NN * 4, stream);
    hipMemsetAsync(stats, 0, 4096 * 4, stream);
    k_indeg<<<EE / 256, 256, 0, stream>>>(dstp, indeg);
    k_scan1<<<256, 256, 0, stream>>>(indeg, bsum);
    k_scan2<<<1, 256, 0, stream>>>(bsum, boff);
    k_scan3<<<256, 256, 0, stream>>>(indeg, boff, rowptr, cursor);
    k_fill<<<EE / 256, 256, 0, stream>>>(srcp, dstp, cursor, csr);
    k_dinv<<<NN / 256, 256, 0, stream>>>(indeg, dinv);

    // weight splits (stacked [Wr | Wl], tiled+swizzled)
    k_wsplit2<<<(384 * 640 + 255) / 256, 256, 0, stream>>>(W1, nullptr, 640, 320, 640, 320, 384, W1h, W1l);
    k_wsplit2<<<(384 * 320 + 255) / 256, 256, 0, stream>>>(Wr2, Wl2, 320, 180, 320, 192, 384, W2h, W2l);
    k_wsplit2<<<(256 * 192 + 255) / 256, 256, 0, stream>>>(Wr3, Wl3, 180, 90, 192, 128, 256, W3h, W3l);
    k_wsplit2<<<(128 * 128 + 255) / 256, 256, 0, stream>>>(Wr4, Wl4, 90, 50, 128, 64, 128, W4h, W4l);

    // layer 1: GCN (640 -> 320).  P = x @ W1 ; Q = gcn_agg(P) + b1 (raw, pre-BN)
    k_gemm_mfma<false, false><<<dim3(1024, 3), 256, 0, stream>>>(
        x, W1h, W1l, 640, 640, nullptr, nullptr, P, nullptr, 320, 320);
    k_gcn_agg320<<<NN / 4, 256, 0, stream>>>(P, rowptr, csr, dinv, b1, Q);
    k_bn_stats<320, 320><<<1024, 256, 0, stream>>>(Q, stats);

    // layer 2: SAGE (320 -> 180, stride 192).  [R | T] = bn(Q) @ [Wr2 | Wl2]; R += mean(T)
    k_gemm_mfma<true, true><<<dim3(1024, 3), 256, 0, stream>>>(
        Q, W2h, W2l, 320, 320, stats, b2, R, T, 180, 192);
    k_agg_add<48, 0><<<NN / 4, 256, 0, stream>>>(T, rowptr, csr, indeg, R);
    k_bn_stats<180, 192><<<1024, 256, 0, stream>>>(R, stats + 1024);

    // layer 3: SAGE (180 -> 90, stride 128).  [P | T] = bn(R) @ [Wr3 | Wl3]; P += mean(T)
    k_gemm_mfma<true, true><<<dim3(1024, 2), 256, 0, stream>>>(
        R, W3h, W3l, 192, 192, stats + 1024, b3, P, T, 90, 128);
    k_agg_add<32, 1><<<NN / 8, 256, 0, stream>>>(T, rowptr, csr, indeg, P);
    k_bn_stats<90, 128><<<1024, 256, 0, stream>>>(P, stats + 2048);

    // layer 4: SAGE (90 -> 50, stride 64).  [Q | T] = bn(P) @ [Wr4 | Wl4]; Q += mean(T)
    k_gemm_mfma<true, true><<<dim3(1024, 1), 256, 0, stream>>>(
        P, W4h, W4l, 128, 128, stats + 2048, b4, Q, T, 50, 64);
    k_agg_add<16, 2><<<NN / 16, 256, 0, stream>>>(T, rowptr, csr, indeg, Q);
    k_bn_stats<50, 64><<<1024, 256, 0, stream>>>(Q, stats + 3072);
    k_bn_apply<64><<<2048, 256, 0, stream>>>(Q, stats + 3072);

    // pooling + head
    hipMemsetAsync(pooled, 0, 16 * 64 * 4, stream);
    k_pool<<<256, 256, 0, stream>>>(Q, pooled);
    k_head<<<1, 256, 0, stream>>>(gender, age, handed, Wq, bq, Wk, bk, Wv, bv,
                                  Wfc, bfc, Wf1, bf1, Wf2, bf2, Wf3, bf3, pooled, dout);
}